// Round 1
// baseline (1096.840 us; speedup 1.0000x reference)
//
#include <hip/hip_runtime.h>
#include <stdint.h>

// LSTM_49357764165950 — MI355X (gfx950)
// Grid: 256 blocks = 32 batch-tiles(32 rows) x 8 gate-chunks(128 gate cols = 4 gates x 32 h-cols)
// Block: 512 thr = 8 waves: w = m + 2*jf + 4*kh  (m: batch 16-row half, jf: h-col 16-half, kh: K half)
// Weights register-resident as bf16 MFMA B-frags; h exchanged per step via agent-scope atomics + per-cluster flag.

typedef float  f32x4  __attribute__((ext_vector_type(4)));
typedef float  f32x2  __attribute__((ext_vector_type(2)));
typedef short  bf16x8 __attribute__((ext_vector_type(8)));

#define XT_OFF    0        // x_tile [32][128] bf16, row stride 256B, XOR-swizzled
#define HT_OFF    8192     // h_tile [32][256] bf16, row stride 512B, XOR-swizzled
#define RB_OFF    24576    // redbuf [4][2][4][64] f32x2 (16KB); prologue-aliased h1f/c1f
#define WM_OFF    40960    // wm0[128], wm1[128], bemb[128] f32
#define SMEM_SZ   86016    // >80KB pad: forces 1 block/CU (spin-sync co-residency + perf uniformity)

#define T_STEPS   255

__device__ __forceinline__ unsigned short f2bf(float f){
  union { float f; unsigned int u; } v; v.f = f;
  unsigned int u = v.u;
  return (unsigned short)((u + 0x7fffu + ((u >> 16) & 1u)) >> 16);   // RTNE
}
__device__ __forceinline__ float sigf(float x){
  float e = __builtin_amdgcn_exp2f(-1.4426950408889634f * x);
  return __builtin_amdgcn_rcpf(1.0f + e);
}
__device__ __forceinline__ float tanh_(float x){
  float e = __builtin_amdgcn_exp2f(-2.8853900817779268f * x);
  return (1.0f - e) * __builtin_amdgcn_rcpf(1.0f + e);
}

__global__ void zero_ws(unsigned int* p){ p[threadIdx.x] = 0u; }

__global__ void __launch_bounds__(512, 2)
lstm_k(const float* __restrict__ obs,
       const float* __restrict__ Wemb, const float* __restrict__ Bemb,
       const float* __restrict__ Wih,  const float* __restrict__ Whh,
       const float* __restrict__ bih,  const float* __restrict__ bhh,
       float* __restrict__ out,
       unsigned int* flags, unsigned int* hbuf)
{
  __shared__ __align__(16) char smem[SMEM_SZ];
  const int tid = threadIdx.x;
  const int l   = tid & 63;
  const int w   = tid >> 6;
  const int m   = w & 1;
  const int jf  = (w >> 1) & 1;
  const int kh  = (w >> 2) & 1;
  const int lc  = l & 15;
  const int lg  = l >> 4;
  const int chunk = blockIdx.x >> 5;   // 0..7  : gate-col chunk (32 h-cols)
  const int tile  = blockIdx.x & 31;   // 0..31 : batch tile. Cluster members share tile,
                                       // blockIdx ≡ tile (mod 8) → same XCD under round-robin.

  // ---- register-resident W fragments (B-operand): 4 N-frags x 6 K-frags, bf16 ----
  bf16x8 wf[4][6];
  #pragma unroll
  for (int ni = 0; ni < 4; ++ni){
    const int rowg = ni*256 + chunk*32 + jf*16 + lc;   // gate row (n-col of MFMA)
    #pragma unroll
    for (int kf = 0; kf < 6; ++kf){
      const int k0 = (kh*6 + kf)*32 + lg*8;            // global K in [0,384)
      const float* src = (k0 < 128) ? (Wih + rowg*128 + k0)
                                    : (Whh + rowg*256 + (k0 - 128));
      f32x4 s0 = *(const f32x4*)(src);
      f32x4 s1 = *(const f32x4*)(src + 4);
      bf16x8 v;
      v[0]=(short)f2bf(s0[0]); v[1]=(short)f2bf(s0[1]);
      v[2]=(short)f2bf(s0[2]); v[3]=(short)f2bf(s0[3]);
      v[4]=(short)f2bf(s1[0]); v[5]=(short)f2bf(s1[1]);
      v[6]=(short)f2bf(s1[2]); v[7]=(short)f2bf(s1[3]);
      wf[ni][kf] = v;
    }
  }
  float bias[4];
  #pragma unroll
  for (int ni = 0; ni < 4; ++ni){
    const int rowg = ni*256 + chunk*32 + jf*16 + lc;
    bias[ni] = bih[rowg] + bhh[rowg];
  }

  // ---- LDS tables + tag-step (x = one-hot at 126; batch-uniform, f32-exact) ----
  float* wm0 = (float*)(smem + WM_OFF);
  float* wm1 = wm0 + 128;
  float* bem = wm0 + 256;
  if (tid < 128){
    float a = 0.f, b = 0.f, c = 0.f;
    if (tid < 126){ a = 4.0f*Wemb[tid]; b = 4.0f*Wemb[126 + tid]; c = Bemb[tid]; }
    wm0[tid] = a; wm1[tid] = b; bem[tid] = c;
  }
  float* h1f = (float*)(smem + RB_OFF);   // aliases redbuf (prologue only)
  float* c1f = h1f + 256;
  if (tid < 256){
    const int j = tid;
    float gi = Wih[(j      )*128 + 126] + bih[j      ] + bhh[j      ];
    float gf = Wih[(256 + j)*128 + 126] + bih[256 + j] + bhh[256 + j]; (void)gf;
    float gg = Wih[(512 + j)*128 + 126] + bih[512 + j] + bhh[512 + j];
    float go = Wih[(768 + j)*128 + 126] + bih[768 + j] + bhh[768 + j];
    float c1 = sigf(gi)*tanh_(gg);        // c0 = 0 => forget term vanishes
    float h1 = sigf(go)*tanh_(c1);
    h1f[j] = h1; c1f[j] = c1;
  }
  __syncthreads();

  // x-tile builder: emb_t = relu(4*vel @ W_emb + b_emb), cols 126/127 stay 0 (tables zero-padded)
  auto xtile = [&](int tt){
    const int row = tid >> 4;
    const int cb  = (tid & 15)*8;
    const int b   = tile*32 + row;
    const float* op = obs + b*512 + tt*2;
    float x0 = op[0], y0 = op[1], x1 = op[2], y1 = op[3];
    float vx = x1 - x0, vy = y1 - y0;
    f32x4 wa = *(const f32x4*)(wm0 + cb);
    f32x4 wb = *(const f32x4*)(wm0 + cb + 4);
    f32x4 wc = *(const f32x4*)(wm1 + cb);
    f32x4 wd = *(const f32x4*)(wm1 + cb + 4);
    f32x4 ba = *(const f32x4*)(bem + cb);
    f32x4 bb = *(const f32x4*)(bem + cb + 4);
    bf16x8 v;
    #pragma unroll
    for (int i = 0; i < 4; ++i){
      float e0 = fmaxf(vx*wa[i] + vy*wc[i] + ba[i], 0.f);
      float e1 = fmaxf(vx*wb[i] + vy*wd[i] + bb[i], 0.f);
      v[i]     = (short)f2bf(e0);
      v[4 + i] = (short)f2bf(e1);
    }
    const int base = XT_OFF + row*256 + cb*2;
    *(bf16x8*)(smem + (base ^ ((row & 7) << 4))) = v;
  };

  // c-state (2 rows per lane: r = 2*kh + {0,1}), h_tile init, x_tile(0)
  float cr0, cr1;
  { const int col = chunk*32 + jf*16 + lc; float cv = c1f[col]; cr0 = cv; cr1 = cv; }
  {
    const int row = tid >> 4, c0 = (tid & 15)*16;
    bf16x8 lo, hi;
    #pragma unroll
    for (int i = 0; i < 8; ++i){ lo[i] = (short)f2bf(h1f[c0 + i]); hi[i] = (short)f2bf(h1f[c0 + 8 + i]); }
    const int sw = (row & 7) << 4;
    const int base = HT_OFF + row*512 + c0*2;
    *(bf16x8*)(smem + (base ^ sw))        = lo;
    *(bf16x8*)(smem + ((base + 16) ^ sw)) = hi;
  }
  xtile(0);
  __syncthreads();

  unsigned int* flag = flags + tile*16;        // 64B-spaced cluster flags
  const int SLOTW = 32*16*256;                 // u32 per hbuf slot (rowpair-packed bf16 pairs)
  float hN0 = 0.f, hN1 = 0.f;
  long spins = 0;

  for (int t = 0; t < T_STEPS; ++t){
    // ---- A: MFMA gates(32x128) = [x|h] @ Wchunk^T  (this wave: its K-half) ----
    f32x4 acc0, acc1, acc2, acc3;
    {
      float b0 = kh ? 0.f : bias[0], b1 = kh ? 0.f : bias[1];
      float b2 = kh ? 0.f : bias[2], b3 = kh ? 0.f : bias[3];
      acc0 = (f32x4){b0,b0,b0,b0}; acc1 = (f32x4){b1,b1,b1,b1};
      acc2 = (f32x4){b2,b2,b2,b2}; acc3 = (f32x4){b3,b3,b3,b3};
    }
    {
      const int rowA = m*16 + lc;
      const int swA  = (rowA & 7) << 4;
      bf16x8 af[6];
      #pragma unroll
      for (int kf = 0; kf < 6; ++kf){
        const int kfi = kh*6 + kf;
        const int addr = (kfi < 4) ? (XT_OFF + rowA*256 + (kfi*32 + lg*8)*2)
                                   : (HT_OFF + rowA*512 + ((kfi - 4)*32 + lg*8)*2);
        af[kf] = *(const bf16x8*)(smem + (addr ^ swA));
      }
      #pragma unroll
      for (int kf = 0; kf < 6; ++kf){
        acc0 = __builtin_amdgcn_mfma_f32_16x16x32_bf16(af[kf], wf[0][kf], acc0, 0, 0, 0);
        acc1 = __builtin_amdgcn_mfma_f32_16x16x32_bf16(af[kf], wf[1][kf], acc1, 0, 0, 0);
        acc2 = __builtin_amdgcn_mfma_f32_16x16x32_bf16(af[kf], wf[2][kf], acc2, 0, 0, 0);
        acc3 = __builtin_amdgcn_mfma_f32_16x16x32_bf16(af[kf], wf[3][kf], acc3, 0, 0, 0);
      }
    }
    // ---- C: export the partner wave's r-half to redbuf (b64, lane-major, conflict-free) ----
    {
      f32x2* rb = (f32x2*)(smem + RB_OFF);
      const int p  = w & 3;
      const int sl = kh ^ 1;
      const int base = ((p*2 + sl)*4)*64 + l;
      f32x2 e0, e1, e2, e3;
      if (kh == 0){
        e0 = (f32x2){acc0[2], acc0[3]}; e1 = (f32x2){acc1[2], acc1[3]};
        e2 = (f32x2){acc2[2], acc2[3]}; e3 = (f32x2){acc3[2], acc3[3]};
      } else {
        e0 = (f32x2){acc0[0], acc0[1]}; e1 = (f32x2){acc1[0], acc1[1]};
        e2 = (f32x2){acc2[0], acc2[1]}; e3 = (f32x2){acc3[0], acc3[1]};
      }
      rb[base] = e0; rb[base + 64] = e1; rb[base + 128] = e2; rb[base + 192] = e3;
    }
    __syncthreads();
    // ---- D: K-reduce own half + LSTM elementwise (c stays f32 in regs) ----
    float hv0, hv1;
    {
      f32x2* rb = (f32x2*)(smem + RB_OFF);
      const int p = w & 3;
      const int base = ((p*2 + kh)*4)*64 + l;
      f32x2 r0 = rb[base], r1 = rb[base + 64], r2 = rb[base + 128], r3 = rb[base + 192];
      float gi0, gi1, gf0, gf1, gg0, gg1, go0, go1;
      if (kh == 0){
        gi0 = acc0[0] + r0[0]; gi1 = acc0[1] + r0[1];
        gf0 = acc1[0] + r1[0]; gf1 = acc1[1] + r1[1];
        gg0 = acc2[0] + r2[0]; gg1 = acc2[1] + r2[1];
        go0 = acc3[0] + r3[0]; go1 = acc3[1] + r3[1];
      } else {
        gi0 = acc0[2] + r0[0]; gi1 = acc0[3] + r0[1];
        gf0 = acc1[2] + r1[0]; gf1 = acc1[3] + r1[1];
        gg0 = acc2[2] + r2[0]; gg1 = acc2[3] + r2[1];
        go0 = acc3[2] + r3[0]; go1 = acc3[3] + r3[1];
      }
      cr0 = sigf(gf0)*cr0 + sigf(gi0)*tanh_(gg0);
      hv0 = sigf(go0)*tanh_(cr0);
      cr1 = sigf(gf1)*cr1 + sigf(gi1)*tanh_(gg1);
      hv1 = sigf(go1)*tanh_(cr1);
    }
    hN0 = hv0; hN1 = hv1;

    if (t < T_STEPS - 1){
      // publish h chunk (rowpair-packed u32, write-through agent atomics)
      {
        const int rp  = m*8 + lg*2 + kh;                 // rowpair: rows 2rp, 2rp+1
        const int col = chunk*32 + jf*16 + lc;
        unsigned int pk = (unsigned int)f2bf(hv0) | ((unsigned int)f2bf(hv1) << 16);
        unsigned int* dst = hbuf + ((t + 1) & 1)*SLOTW + tile*4096 + rp*256 + col;
        __hip_atomic_store(dst, pk, __ATOMIC_RELAXED, __HIP_MEMORY_SCOPE_AGENT);
      }
      xtile(t + 1);                                      // overlap with store latency
      __syncthreads();                                   // all stores vmcnt-drained
      if (tid == 0){
        __hip_atomic_fetch_add(flag, 1u, __ATOMIC_RELAXED, __HIP_MEMORY_SCOPE_AGENT);
        const unsigned int tgt = 8u*(unsigned)(t + 1);
        while (__hip_atomic_load(flag, __ATOMIC_RELAXED, __HIP_MEMORY_SCOPE_AGENT) < tgt){
          __builtin_amdgcn_s_sleep(1);
          if (++spins > 10000000L) break;                // sticky global budget: no infinite hang
        }
      }
      __syncthreads();
      // gather full h(32x256) for next step into swizzled h_tile
      {
        const int rp = tid >> 5;
        const int c0 = (tid & 31)*8;
        unsigned int* src = hbuf + ((t + 1) & 1)*SLOTW + tile*4096 + rp*256 + c0;
        unsigned int wv[8];
        #pragma unroll
        for (int i = 0; i < 8; ++i)
          wv[i] = __hip_atomic_load(src + i, __ATOMIC_RELAXED, __HIP_MEMORY_SCOPE_AGENT);
        bf16x8 lo, hi;
        #pragma unroll
        for (int i = 0; i < 8; ++i){ lo[i] = (short)(wv[i] & 0xffffu); hi[i] = (short)(wv[i] >> 16); }
        const int r0 = rp*2, r1 = rp*2 + 1;
        const int b0 = HT_OFF + r0*512 + c0*2;
        const int b1 = HT_OFF + r1*512 + c0*2;
        *(bf16x8*)(smem + (b0 ^ ((r0 & 7) << 4))) = lo;
        *(bf16x8*)(smem + (b1 ^ ((r1 & 7) << 4))) = hi;
      }
      __syncthreads();
    }
  }

  // ---- epilogue: final (h, c) in f32 ----
  {
    const int row0 = tile*32 + m*16 + lg*4 + 2*kh;
    const int col  = chunk*32 + jf*16 + lc;
    out[row0*256 + col]                = hN0;
    out[(row0 + 1)*256 + col]          = hN1;
    out[262144 + row0*256 + col]       = cr0;
    out[262144 + (row0 + 1)*256 + col] = cr1;
  }
}

extern "C" void kernel_launch(void* const* d_in, const int* in_sizes, int n_in,
                              void* d_out, int out_size, void* d_ws, size_t ws_size,
                              hipStream_t stream) {
  (void)in_sizes; (void)n_in; (void)out_size; (void)ws_size;
  const float* obs  = (const float*)d_in[0];
  /* d_in[1] = pooled: unused by reference */
  const float* Wemb = (const float*)d_in[2];
  const float* Bemb = (const float*)d_in[3];
  const float* Wih  = (const float*)d_in[4];
  const float* Whh  = (const float*)d_in[5];
  const float* bih  = (const float*)d_in[6];
  const float* bhh  = (const float*)d_in[7];
  float* out = (float*)d_out;
  unsigned int* flags = (unsigned int*)d_ws;                       // 2KB used (zeroed every launch)
  unsigned int* hbuf  = (unsigned int*)((char*)d_ws + 4096);       // 2 x 512KB h slots

  zero_ws<<<dim3(1), dim3(512), 0, stream>>>(flags);
  lstm_k<<<dim3(256), dim3(512), 0, stream>>>(obs, Wemb, Bemb, Wih, Whh, bih, bhh,
                                              out, flags, hbuf);
}

// Round 2
// 1033.985 us; speedup vs baseline: 1.0608x; 1.0608x over previous
//
#include <hip/hip_runtime.h>
#include <stdint.h>

// LSTM_49357764165950 — MI355X (gfx950), round 2
// Grid: 256 blocks = 32 batch-tiles(32 rows) x 8 gate-chunks(32 h-cols x 4 gates).
// Block: 256 thr = 4 waves (m: batch 16-half, hf: h-col 16-half). Each wave: all 4 gates,
// full K=384 (12 MFMA K-frags), so i/f/g/o are same-lane -> no K-reduce, no redbuf.
// Weights register-resident: wf[4][12] bf16x8 = 192 VGPR/thread.
// h-exchange: per-producer-WAVE seq words (agent atomics). Producer: data stores ->
// per-wave s_waitcnt vmcnt(0) -> lane0 seq=t+1. Consumer threads each poll exactly the
// one producer wave they depend on, then gather. Double-buffered x/h LDS tiles ->
// ONE __syncthreads per step.
//
// Slot-reuse safety: block B reaches iter-t stores only after its poll@t-1 saw all 32
// producer-wave seqs >= t; wave publishes seq=t only after passing its block's
// end-of-iter-(t-2) barrier, which is after that block finished reading slot((t+1)&1)'s
// old data (gathered h_{t-1} at iter t-2). So overwrite happens-after all old reads.

typedef float  f32x4  __attribute__((ext_vector_type(4)));
typedef float  f32x2  __attribute__((ext_vector_type(2)));
typedef short  bf16x8 __attribute__((ext_vector_type(8)));

#define SMEM_SZ 86016      // >80KB: force 1 block/CU (co-residency for spin protocol)
#define T_STEPS 255
// LDS map (double-buffered tiles, XOR-swizzled byte^((row&7)<<4))
#define XT(b)   ((b)*8192)             // x_tile[2]: [32][128] bf16, row stride 256B
#define HT(b)   (16384 + (b)*16384)    // h_tile[2]: [32][256] bf16, row stride 512B
#define WM_OFF  49152                  // wm0[128] wm1[128] bem[128] f32
#define H1_OFF  51200                  // h1f[256] f32 (tag-step h)
#define C1_OFF  52224                  // c1f[256] f32 (tag-step c)

__device__ __forceinline__ unsigned short f2bf(float f){
  union { float f; unsigned int u; } v; v.f = f;
  unsigned int u = v.u;
  return (unsigned short)((u + 0x7fffu + ((u >> 16) & 1u)) >> 16);   // RTNE
}
__device__ __forceinline__ float sigf(float x){
  float e = __builtin_amdgcn_exp2f(-1.4426950408889634f * x);
  return __builtin_amdgcn_rcpf(1.0f + e);
}
__device__ __forceinline__ float tanh_(float x){
  float e = __builtin_amdgcn_exp2f(-2.8853900817779268f * x);
  return (1.0f - e) * __builtin_amdgcn_rcpf(1.0f + e);
}

__global__ void zero_ws(unsigned int* p){ p[blockIdx.x*512 + threadIdx.x] = 0u; }

__global__ void __launch_bounds__(256, 1)
lstm_k(const float* __restrict__ obs,
       const float* __restrict__ Wemb, const float* __restrict__ Bemb,
       const float* __restrict__ Wih,  const float* __restrict__ Whh,
       const float* __restrict__ bih,  const float* __restrict__ bhh,
       float* __restrict__ out,
       unsigned int* flags, unsigned int* hbuf)
{
  __shared__ __align__(16) char smem[SMEM_SZ];
  const int tid = threadIdx.x;
  const int l   = tid & 63;
  const int w   = tid >> 6;
  const int m   = w & 1;         // batch 16-row half
  const int hf  = w >> 1;        // h-col 16-half of the chunk's 32 cols
  const int lc  = l & 15;
  const int lg  = l >> 4;
  const int chunk = blockIdx.x >> 5;   // 0..7 gate-col chunk (32 h-cols x 4 gates)
  const int tile  = blockIdx.x & 31;   // 0..31 batch tile

  // ---- register-resident W fragments (B-operand): 4 gates x 12 K-frags ----
  bf16x8 wf[4][12];
  #pragma unroll
  for (int ni = 0; ni < 4; ++ni){
    const int rowg = ni*256 + chunk*32 + hf*16 + lc;
    #pragma unroll
    for (int kf = 0; kf < 12; ++kf){
      const int k0 = kf*32 + lg*8;                 // K in [0,384): 0..127 x, 128.. h
      const float* src = (k0 < 128) ? (Wih + rowg*128 + k0)
                                    : (Whh + rowg*256 + (k0 - 128));
      f32x4 s0 = *(const f32x4*)(src);
      f32x4 s1 = *(const f32x4*)(src + 4);
      bf16x8 v;
      v[0]=(short)f2bf(s0[0]); v[1]=(short)f2bf(s0[1]);
      v[2]=(short)f2bf(s0[2]); v[3]=(short)f2bf(s0[3]);
      v[4]=(short)f2bf(s1[0]); v[5]=(short)f2bf(s1[1]);
      v[6]=(short)f2bf(s1[2]); v[7]=(short)f2bf(s1[3]);
      wf[ni][kf] = v;
    }
  }
  float bias[4];
  #pragma unroll
  for (int ni = 0; ni < 4; ++ni){
    const int rowg = ni*256 + chunk*32 + hf*16 + lc;
    bias[ni] = bih[rowg] + bhh[rowg];
  }

  // ---- LDS tables + tag step (x one-hot at col 126; batch-uniform, f32-exact) ----
  float* wm0 = (float*)(smem + WM_OFF);
  float* wm1 = wm0 + 128;
  float* bem = wm0 + 256;
  if (tid < 128){
    float a = 0.f, b = 0.f, c = 0.f;
    if (tid < 126){ a = 4.0f*Wemb[tid]; b = 4.0f*Wemb[126 + tid]; c = Bemb[tid]; }
    wm0[tid] = a; wm1[tid] = b; bem[tid] = c;
  }
  float* h1f = (float*)(smem + H1_OFF);
  float* c1f = (float*)(smem + C1_OFF);
  {
    const int j = tid;   // 256 threads cover H=256
    float gi = Wih[(j      )*128 + 126] + bih[j      ] + bhh[j      ];
    float gg = Wih[(512 + j)*128 + 126] + bih[512 + j] + bhh[512 + j];
    float go = Wih[(768 + j)*128 + 126] + bih[768 + j] + bhh[768 + j];
    float c1 = sigf(gi)*tanh_(gg);       // c0 = 0 -> forget term vanishes
    h1f[j] = sigf(go)*tanh_(c1); c1f[j] = c1;
  }
  __syncthreads();

  // x-tile builder into buffer `buf` (cols 126/127 stay 0 via zero-padded tables)
  auto xtile = [&](int tt, int buf){
    const int row = tid >> 3;
    const int cb  = (tid & 7) * 16;
    const int b   = tile*32 + row;
    const float* op = obs + b*512 + tt*2;
    f32x2 p0 = *(const f32x2*)(op);
    f32x2 p1 = *(const f32x2*)(op + 2);
    const float vx = p1[0] - p0[0], vy = p1[1] - p0[1];
    const int sw = (row & 7) << 4;
    #pragma unroll
    for (int hb = 0; hb < 2; ++hb){
      const int c = cb + hb*8;
      f32x4 wa = *(const f32x4*)(wm0 + c), wb = *(const f32x4*)(wm0 + c + 4);
      f32x4 wc = *(const f32x4*)(wm1 + c), wd = *(const f32x4*)(wm1 + c + 4);
      f32x4 ba = *(const f32x4*)(bem + c), bb = *(const f32x4*)(bem + c + 4);
      bf16x8 v;
      #pragma unroll
      for (int i = 0; i < 4; ++i){
        float e0 = fmaxf(vx*wa[i] + vy*wc[i] + ba[i], 0.f);
        float e1 = fmaxf(vx*wb[i] + vy*wd[i] + bb[i], 0.f);
        v[i] = (short)f2bf(e0); v[4 + i] = (short)f2bf(e1);
      }
      const int base = XT(buf) + row*256 + c*2;
      *(bf16x8*)(smem + (base ^ sw)) = v;
    }
  };

  // consumer/gather mapping (also used for h_tile[0] init)
  const int g_rp   = tid >> 4;          // rowpair 0..15
  const int g_half = (tid >> 3) & 1;    // which 16-col half of the chunk
  const int g_ch   = tid & 7;           // chunk
  const int g_c0   = g_ch*32 + g_half*16;

  // c-state init (batch-uniform) + h_tile[0] + x_tile[0]
  const int col = chunk*32 + hf*16 + lc;
  float cs[4];
  { float cv = c1f[col]; cs[0]=cv; cs[1]=cv; cs[2]=cv; cs[3]=cv; }
  {
    bf16x8 A, B;
    #pragma unroll
    for (int i = 0; i < 8; ++i){ A[i] = (short)f2bf(h1f[g_c0 + i]); B[i] = (short)f2bf(h1f[g_c0 + 8 + i]); }
    const int r0 = g_rp*2, r1 = r0 + 1;
    const int b0 = HT(0) + r0*512 + g_c0*2, s0 = (r0 & 7) << 4;
    const int b1 = HT(0) + r1*512 + g_c0*2, s1 = (r1 & 7) << 4;
    *(bf16x8*)(smem + (b0 ^ s0)) = A; *(bf16x8*)(smem + ((b0 + 16) ^ s0)) = B;
    *(bf16x8*)(smem + (b1 ^ s1)) = A; *(bf16x8*)(smem + ((b1 + 16) ^ s1)) = B;
  }
  xtile(0, 0);
  __syncthreads();

  unsigned int* my_seq   = flags + (tile*32 + chunk*4 + m*2 + hf)*16;           // producer wave
  unsigned int* poll_seq = flags + (tile*32 + g_ch*4 + (g_rp>>3)*2 + g_half)*16; // the wave I consume
  float hv[4] = {0.f, 0.f, 0.f, 0.f};
  long guard = 0;

  for (int t = 0; t < T_STEPS; ++t){
    const int cur = t & 1;
    // ---- MFMA: gates(16x64 per wave) = [x|h] @ W^T, K=384 ----
    f32x4 acc0 = (f32x4){bias[0],bias[0],bias[0],bias[0]};
    f32x4 acc1 = (f32x4){bias[1],bias[1],bias[1],bias[1]};
    f32x4 acc2 = (f32x4){bias[2],bias[2],bias[2],bias[2]};
    f32x4 acc3 = (f32x4){bias[3],bias[3],bias[3],bias[3]};
    {
      const int rowA = m*16 + lc;
      const int swA  = (rowA & 7) << 4;
      #pragma unroll
      for (int kf = 0; kf < 12; ++kf){
        const int addr = (kf < 4) ? (XT(cur) + rowA*256 + kf*64 + lg*16)
                                  : (HT(cur) + rowA*512 + (kf - 4)*64 + lg*16);
        bf16x8 a = *(const bf16x8*)(smem + (addr ^ swA));
        acc0 = __builtin_amdgcn_mfma_f32_16x16x32_bf16(a, wf[0][kf], acc0, 0, 0, 0);
        acc1 = __builtin_amdgcn_mfma_f32_16x16x32_bf16(a, wf[1][kf], acc1, 0, 0, 0);
        acc2 = __builtin_amdgcn_mfma_f32_16x16x32_bf16(a, wf[2][kf], acc2, 0, 0, 0);
        acc3 = __builtin_amdgcn_mfma_f32_16x16x32_bf16(a, wf[3][kf], acc3, 0, 0, 0);
      }
    }
    // ---- elementwise (C-layout: reg r -> row lg*4+r, col lc; rows are batch) ----
    #pragma unroll
    for (int r = 0; r < 4; ++r){
      cs[r] = sigf(acc1[r])*cs[r] + sigf(acc0[r])*tanh_(acc2[r]);
      hv[r] = sigf(acc3[r])*tanh_(cs[r]);
    }

    if (t < T_STEPS - 1){
      const int slot = (t + 1) & 1;
      // publish: rowpair-packed u32, per-wave drain, then lane0 seq
      {
        const int rp0 = m*8 + lg*2;
        unsigned int pk01 = (unsigned int)f2bf(hv[0]) | ((unsigned int)f2bf(hv[1]) << 16);
        unsigned int pk23 = (unsigned int)f2bf(hv[2]) | ((unsigned int)f2bf(hv[3]) << 16);
        unsigned int* dst = hbuf + slot*131072 + tile*4096 + rp0*256 + col;
        __hip_atomic_store(dst,       pk01, __ATOMIC_RELAXED, __HIP_MEMORY_SCOPE_AGENT);
        __hip_atomic_store(dst + 256, pk23, __ATOMIC_RELAXED, __HIP_MEMORY_SCOPE_AGENT);
      }
      asm volatile("s_waitcnt vmcnt(0)" ::: "memory");   // wave's stores acked at coherence point
      if (l == 0)
        __hip_atomic_store(my_seq, (unsigned)(t + 1), __ATOMIC_RELAXED, __HIP_MEMORY_SCOPE_AGENT);

      xtile(t + 1, slot);            // VALU work overlaps seq-store flight

      // poll the single producer wave this thread consumes, then gather 16 u32
      {
        const unsigned tgt = (unsigned)(t + 1);
        while (__hip_atomic_load(poll_seq, __ATOMIC_RELAXED, __HIP_MEMORY_SCOPE_AGENT) < tgt){
          __builtin_amdgcn_s_sleep(1);
          if (++guard > 2000000L) break;   // sticky budget: no infinite hang
        }
        const unsigned int* src = hbuf + slot*131072 + tile*4096 + g_rp*256 + g_c0;
        unsigned int wv[16];
        #pragma unroll
        for (int i = 0; i < 16; ++i)
          wv[i] = __hip_atomic_load(src + i, __ATOMIC_RELAXED, __HIP_MEMORY_SCOPE_AGENT);
        bf16x8 loA, loB, hiA, hiB;
        #pragma unroll
        for (int i = 0; i < 8; ++i){
          loA[i] = (short)(wv[i] & 0xffffu);     hiA[i] = (short)(wv[i] >> 16);
          loB[i] = (short)(wv[8 + i] & 0xffffu); hiB[i] = (short)(wv[8 + i] >> 16);
        }
        const int r0 = g_rp*2, r1 = r0 + 1;
        const int b0 = HT(slot) + r0*512 + g_c0*2, s0 = (r0 & 7) << 4;
        const int b1 = HT(slot) + r1*512 + g_c0*2, s1 = (r1 & 7) << 4;
        *(bf16x8*)(smem + (b0 ^ s0)) = loA; *(bf16x8*)(smem + ((b0 + 16) ^ s0)) = loB;
        *(bf16x8*)(smem + (b1 ^ s1)) = hiA; *(bf16x8*)(smem + ((b1 + 16) ^ s1)) = hiB;
      }
    }
    __syncthreads();                 // the ONE barrier per step
  }

  // ---- epilogue: final (h, c) f32 ----
  {
    const int row0 = tile*32 + m*16 + lg*4;
    #pragma unroll
    for (int r = 0; r < 4; ++r){
      out[(row0 + r)*256 + col]          = hv[r];
      out[262144 + (row0 + r)*256 + col] = cs[r];
    }
  }
}

extern "C" void kernel_launch(void* const* d_in, const int* in_sizes, int n_in,
                              void* d_out, int out_size, void* d_ws, size_t ws_size,
                              hipStream_t stream) {
  (void)in_sizes; (void)n_in; (void)out_size; (void)ws_size;
  const float* obs  = (const float*)d_in[0];
  /* d_in[1] = pooled: unused by reference */
  const float* Wemb = (const float*)d_in[2];
  const float* Bemb = (const float*)d_in[3];
  const float* Wih  = (const float*)d_in[4];
  const float* Whh  = (const float*)d_in[5];
  const float* bih  = (const float*)d_in[6];
  const float* bhh  = (const float*)d_in[7];
  float* out = (float*)d_out;
  unsigned int* flags = (unsigned int*)d_ws;                   // 64KB seq words (re-zeroed each launch)
  unsigned int* hbuf  = (unsigned int*)((char*)d_ws + 65536);  // 2 x 512KB h slots

  zero_ws<<<dim3(32), dim3(512), 0, stream>>>(flags);
  lstm_k<<<dim3(256), dim3(256), 0, stream>>>(obs, Wemb, Bemb, Wih, Whh, bih, bhh,
                                              out, flags, hbuf);
}

// Round 4
// 987.820 us; speedup vs baseline: 1.1104x; 1.0467x over previous
//
#include <hip/hip_runtime.h>
#include <stdint.h>

// LSTM_49357764165950 — MI355X (gfx950), round 4
// Grid: 256 blocks = 32 batch-tiles(32 rows) x 8 gate-chunks. Block: 256 thr = 4 waves.
// Weights register-resident wf[4][12] (bf16 B-frags). Per-wave: all 4 gates, K=384.
//
// h-exchange: SELF-VALIDATING TAGGED WORDS. Each u32 = (tag=t+1)<<16 | bf16(h).
// 4B stores are atomic -> tag+payload travel together; NO ordering requirements,
// no seq words, no vmcnt drains. Consumer retries until all its 32 tags == t+1.
// Fast path (tile's 8 blocks verified same-XCD at runtime): sc0 stores + sc0 nt loads
// (XCD-local L2 coherence point). Fallback: agent-scope relaxed atomics (memory-side,
// correct for any placement). Two agreement rounds make the decision tile-uniform.
//
// Tag buffer = d_out itself: slot0 (words 0..262143) == h-region, slot1 == c-region.
// Per-tile done-rendezvous before the epilogue overwrites slot0. zero_ws re-zeroes
// d_out+flags each launch (agent stores: no dirty remote-L2 copies, kills stale tags).
//
// Slot-reuse safety (2 slots): writer overwrites slot s (tag t+3) only after its
// gather of tag t+2 succeeded => every partner published t+2 => every partner passed
// its end-of-iter-(t) barrier => every partner's slot-s gather (tag t+1) completed.

typedef float  f32x4  __attribute__((ext_vector_type(4)));
typedef float  f32x2  __attribute__((ext_vector_type(2)));
typedef short  bf16x8 __attribute__((ext_vector_type(8)));
typedef unsigned int u32x4 __attribute__((ext_vector_type(4)));

#define SMEM_SZ 86016      // >80KB: force 1 block/CU (co-residency + full CU per block)
#define T_STEPS 255
#define FRAG    2064       // 32 cols x 32 rows x 2B + 16B pad
#define XT(b)   ((b)*4*FRAG)              // x frags kf 0..3
#define HT(b)   (16512 + (b)*8*FRAG)      // h frags kf 0..7
#define WM_OFF  49536                     // wm0[128] wm1[128] bem[128] f32 (also xs scratch)
#define H1_OFF  51072
#define C1_OFF  52096

#define AG_ST(p, v) __hip_atomic_store((p), (v), __ATOMIC_RELAXED, __HIP_MEMORY_SCOPE_AGENT)
#define AG_LD(p)    __hip_atomic_load((p),        __ATOMIC_RELAXED, __HIP_MEMORY_SCOPE_AGENT)

__device__ __forceinline__ unsigned short f2bf(float f){
  union { float f; unsigned int u; } v; v.f = f;
  unsigned int u = v.u;
  return (unsigned short)((u + 0x7fffu + ((u >> 16) & 1u)) >> 16);   // RTNE
}
__device__ __forceinline__ float sigf(float x){
  float e = __builtin_amdgcn_exp2f(-1.4426950408889634f * x);
  return __builtin_amdgcn_rcpf(1.0f + e);
}
__device__ __forceinline__ float tanh_(float x){
  float e = __builtin_amdgcn_exp2f(-2.8853900817779268f * x);
  return (1.0f - e) * __builtin_amdgcn_rcpf(1.0f + e);
}

// zero flags (16384 u32) + d_out (524288 u32) with agent stores (write-through; no
// dirty L2 copies anywhere -> no stale-eviction hazard for the tagged exchange).
__global__ void zero_ws(unsigned int* flags, unsigned int* outw){
  const unsigned idx = blockIdx.x*512u + threadIdx.x;
  if (idx < 16384u)        AG_ST(flags + idx, 0u);
  else if (idx < 540672u)  AG_ST(outw + (idx - 16384u), 0u);
}

__global__ void __launch_bounds__(256, 1)
lstm_k(const float* __restrict__ obs,
       const float* __restrict__ Wemb, const float* __restrict__ Bemb,
       const float* __restrict__ Wih,  const float* __restrict__ Whh,
       const float* __restrict__ bih,  const float* __restrict__ bhh,
       float* out, unsigned int* flags, unsigned int* hbuf)   // hbuf aliases out!
{
  __shared__ __align__(16) char smem[SMEM_SZ];
  const int tid = threadIdx.x;
  const int l   = tid & 63;
  const int w   = tid >> 6;
  const int m   = w & 1;
  const int hf  = w >> 1;
  const int lc  = l & 15;
  const int lg  = l >> 4;
  const int chunk = blockIdx.x >> 5;
  const int tile  = blockIdx.x & 31;     // partners {tile+32k} share blockIdx%8

  // ---- XCD-affinity check, 2 rounds (decision provably tile-uniform) ----
  unsigned xcc;
  asm volatile("s_getreg_b32 %0, hwreg(HW_REG_XCC_ID)" : "=s"(xcc));
  bool fast;
  {
    volatile unsigned* xs = (volatile unsigned*)(smem + WM_OFF);
    // round 1: publish 1+xcc, read all 8
    if (tid == 0) AG_ST(flags + (tile*8 + chunk)*16 + 8, 1u + xcc);
    if (tid < 8){
      unsigned v; long g = 0;
      do { v = AG_LD(flags + (tile*8 + tid)*16 + 8); } while (v == 0 && ++g < 10000000L);
      xs[tid] = v;
    }
    __syncthreads();
    unsigned ok = 1;
    #pragma unroll
    for (int j = 0; j < 8; ++j) ok &= (xs[j] == 1u + xcc) ? 1u : 0u;
    __syncthreads();
    // round 2: publish ok(2)/not-ok(1), read all 8 -> uniform decision
    if (tid == 0) AG_ST(flags + (tile*8 + chunk)*16 + 9, ok ? 2u : 1u);
    if (tid < 8){
      unsigned v; long g = 0;
      do { v = AG_LD(flags + (tile*8 + tid)*16 + 9); } while (v == 0 && ++g < 10000000L);
      xs[tid] = v;
    }
    __syncthreads();
    unsigned all2 = 1;
    #pragma unroll
    for (int j = 0; j < 8; ++j) all2 &= (xs[j] == 2u) ? 1u : 0u;
    fast = (all2 != 0);
    __syncthreads();                       // before WM area reuse
  }

  // ---- register-resident W fragments ----
  bf16x8 wf[4][12];
  #pragma unroll
  for (int ni = 0; ni < 4; ++ni){
    const int rowg = ni*256 + chunk*32 + hf*16 + lc;
    #pragma unroll
    for (int kf = 0; kf < 12; ++kf){
      const int k0 = kf*32 + lg*8;
      const float* src = (k0 < 128) ? (Wih + rowg*128 + k0)
                                    : (Whh + rowg*256 + (k0 - 128));
      f32x4 s0 = *(const f32x4*)(src);
      f32x4 s1 = *(const f32x4*)(src + 4);
      bf16x8 v;
      v[0]=(short)f2bf(s0[0]); v[1]=(short)f2bf(s0[1]);
      v[2]=(short)f2bf(s0[2]); v[3]=(short)f2bf(s0[3]);
      v[4]=(short)f2bf(s1[0]); v[5]=(short)f2bf(s1[1]);
      v[6]=(short)f2bf(s1[2]); v[7]=(short)f2bf(s1[3]);
      wf[ni][kf] = v;
    }
  }
  float bias[4];
  #pragma unroll
  for (int ni = 0; ni < 4; ++ni){
    const int rowg = ni*256 + chunk*32 + hf*16 + lc;
    bias[ni] = bih[rowg] + bhh[rowg];
  }

  // ---- LDS tables + tag step ----
  float* wm0 = (float*)(smem + WM_OFF);
  float* wm1 = wm0 + 128;
  float* bem = wm0 + 256;
  if (tid < 128){
    float a = 0.f, b = 0.f, c = 0.f;
    if (tid < 126){ a = 4.0f*Wemb[tid]; b = 4.0f*Wemb[126 + tid]; c = Bemb[tid]; }
    wm0[tid] = a; wm1[tid] = b; bem[tid] = c;
  }
  float* h1f = (float*)(smem + H1_OFF);
  float* c1f = (float*)(smem + C1_OFF);
  {
    const int j = tid;
    float gi = Wih[(j      )*128 + 126] + bih[j      ] + bhh[j      ];
    float gg = Wih[(512 + j)*128 + 126] + bih[512 + j] + bhh[512 + j];
    float go = Wih[(768 + j)*128 + 126] + bih[768 + j] + bhh[768 + j];
    float c1 = sigf(gi)*tanh_(gg);
    h1f[j] = sigf(go)*tanh_(c1); c1f[j] = c1;
  }
  __syncthreads();

  // x-tile builder (frag layout)
  auto xtile = [&](int buf, float vx, float vy){
    const int row = tid >> 3;
    const int kf  = (tid & 7) >> 1;
    const int lgb = (tid & 1) * 2;
    const int c0  = kf*32 + lgb*8;
    f32x4 wa = *(const f32x4*)(wm0 + c0), wb = *(const f32x4*)(wm0 + c0 + 4);
    f32x4 wc = *(const f32x4*)(wm1 + c0), wd = *(const f32x4*)(wm1 + c0 + 4);
    f32x4 ba = *(const f32x4*)(bem + c0), bb = *(const f32x4*)(bem + c0 + 4);
    f32x4 we = *(const f32x4*)(wm0 + c0 + 8), wg = *(const f32x4*)(wm0 + c0 + 12);
    f32x4 wh = *(const f32x4*)(wm1 + c0 + 8), wi = *(const f32x4*)(wm1 + c0 + 12);
    f32x4 bc = *(const f32x4*)(bem + c0 + 8), bd = *(const f32x4*)(bem + c0 + 12);
    bf16x8 v0, v1;
    #pragma unroll
    for (int i = 0; i < 4; ++i){
      v0[i]     = (short)f2bf(fmaxf(vx*wa[i] + vy*wc[i] + ba[i], 0.f));
      v0[4 + i] = (short)f2bf(fmaxf(vx*wb[i] + vy*wd[i] + bb[i], 0.f));
      v1[i]     = (short)f2bf(fmaxf(vx*we[i] + vy*wh[i] + bc[i], 0.f));
      v1[4 + i] = (short)f2bf(fmaxf(vx*wg[i] + vy*wi[i] + bd[i], 0.f));
    }
    char* p = smem + XT(buf) + kf*FRAG + row*64 + lgb*16;
    *(bf16x8*)(p)      = v0;
    *(bf16x8*)(p + 16) = v1;
  };

  // gather mapping: thread owns (row gr, frag gg) = 32 cols
  const int gr = tid >> 3;
  const int gg = tid & 7;

  // c-state + h_tile[0] + x_tile[0]
  const int col = chunk*32 + hf*16 + lc;
  float cs[4];
  { float cv = c1f[col]; cs[0]=cv; cs[1]=cv; cs[2]=cv; cs[3]=cv; }
  {
    const int hc0 = gg*32;               // frag gg covers h cols gg*32..+31
    bf16x8 v0, v1, v2, v3;
    #pragma unroll
    for (int i = 0; i < 8; ++i){
      v0[i] = (short)f2bf(h1f[hc0 + i]);      v1[i] = (short)f2bf(h1f[hc0 + 8 + i]);
      v2[i] = (short)f2bf(h1f[hc0 + 16 + i]); v3[i] = (short)f2bf(h1f[hc0 + 24 + i]);
    }
    char* pb = smem + HT(0) + gg*FRAG + gr*64;
    *(bf16x8*)(pb) = v0; *(bf16x8*)(pb+16) = v1; *(bf16x8*)(pb+32) = v2; *(bf16x8*)(pb+48) = v3;
  }
  {
    const float* op = obs + (tile*32 + (tid >> 3))*512;
    f32x2 p0 = *(const f32x2*)(op), p1 = *(const f32x2*)(op + 2);
    xtile(0, p1[0] - p0[0], p1[1] - p0[1]);
  }
  __syncthreads();

  float hv[4] = {0.f, 0.f, 0.f, 0.f};
  long guard = 0;
  const int prow = m*16 + lg*4;          // first of this lane's 4 batch rows

  for (int t = 0; t < T_STEPS; ++t){
    const int cur = t & 1;
    float vx = 0.f, vy = 0.f;
    if (t < T_STEPS - 1){
      const float* op = obs + (tile*32 + (tid >> 3))*512 + (t + 1)*2;
      f32x2 p0 = *(const f32x2*)(op), p1 = *(const f32x2*)(op + 2);
      vx = p1[0] - p0[0]; vy = p1[1] - p0[1];
    }
    // ---- MFMA ----
    f32x4 acc0 = (f32x4){bias[0],bias[0],bias[0],bias[0]};
    f32x4 acc1 = (f32x4){bias[1],bias[1],bias[1],bias[1]};
    f32x4 acc2 = (f32x4){bias[2],bias[2],bias[2],bias[2]};
    f32x4 acc3 = (f32x4){bias[3],bias[3],bias[3],bias[3]};
    {
      const int rowA = m*16 + lc;
      #pragma unroll
      for (int kf = 0; kf < 12; ++kf){
        const char* pa = smem + ((kf < 4) ? (XT(cur) + kf*FRAG)
                                          : (HT(cur) + (kf - 4)*FRAG))
                              + rowA*64 + lg*16;
        bf16x8 a = *(const bf16x8*)pa;
        acc0 = __builtin_amdgcn_mfma_f32_16x16x32_bf16(a, wf[0][kf], acc0, 0, 0, 0);
        acc1 = __builtin_amdgcn_mfma_f32_16x16x32_bf16(a, wf[1][kf], acc1, 0, 0, 0);
        acc2 = __builtin_amdgcn_mfma_f32_16x16x32_bf16(a, wf[2][kf], acc2, 0, 0, 0);
        acc3 = __builtin_amdgcn_mfma_f32_16x16x32_bf16(a, wf[3][kf], acc3, 0, 0, 0);
      }
    }
    // ---- elementwise ----
    #pragma unroll
    for (int r = 0; r < 4; ++r){
      cs[r] = sigf(acc1[r])*cs[r] + sigf(acc0[r])*tanh_(acc2[r]);
      hv[r] = sigf(acc3[r])*tanh_(cs[r]);
    }

    if (t < T_STEPS - 1){
      const int slot = (t + 1) & 1;
      const unsigned want = ((unsigned)(t + 1)) << 16;

      // ---- publish: 4 tagged words, rows prow..prow+3 ----
      {
        unsigned w0 = want | f2bf(hv[0]);
        unsigned w1 = want | f2bf(hv[1]);
        unsigned w2 = want | f2bf(hv[2]);
        unsigned w3 = want | f2bf(hv[3]);
        unsigned int* dst = hbuf + slot*262144 + tile*8192 + prow*256 + col;
        if (fast){
          asm volatile("global_store_dword %0, %1, off sc0\n\t"
                       "global_store_dword %0, %2, off offset:1024 sc0\n\t"
                       "global_store_dword %0, %3, off offset:2048 sc0\n\t"
                       "global_store_dword %0, %4, off offset:3072 sc0"
                       :: "v"(dst), "v"(w0), "v"(w1), "v"(w2), "v"(w3) : "memory");
        } else {
          AG_ST(dst,       w0); AG_ST(dst + 256, w1);
          AG_ST(dst + 512, w2); AG_ST(dst + 768, w3);
        }
      }

      xtile(slot, vx, vy);               // overlaps partners' publish flight

      // ---- gather with per-word tag validation ----
      {
        const unsigned int* src = hbuf + slot*262144 + tile*8192 + gr*256 + gg*32;
        u32x4 q0, q1, q2, q3, q4, q5, q6, q7;
        unsigned bad;
        do {
          if (fast){
            asm volatile(
              "global_load_dwordx4 %0, %8, off sc0 nt\n\t"
              "global_load_dwordx4 %1, %8, off offset:16 sc0 nt\n\t"
              "global_load_dwordx4 %2, %8, off offset:32 sc0 nt\n\t"
              "global_load_dwordx4 %3, %8, off offset:48 sc0 nt\n\t"
              "global_load_dwordx4 %4, %8, off offset:64 sc0 nt\n\t"
              "global_load_dwordx4 %5, %8, off offset:80 sc0 nt\n\t"
              "global_load_dwordx4 %6, %8, off offset:96 sc0 nt\n\t"
              "global_load_dwordx4 %7, %8, off offset:112 sc0 nt\n\t"
              "s_waitcnt vmcnt(0)"
              : "=&v"(q0), "=&v"(q1), "=&v"(q2), "=&v"(q3),
                "=&v"(q4), "=&v"(q5), "=&v"(q6), "=&v"(q7)
              : "v"(src) : "memory");
          } else {
            #pragma unroll
            for (int i = 0; i < 4; ++i){
              q0[i] = AG_LD(src +      i); q1[i] = AG_LD(src +  4 + i);
              q2[i] = AG_LD(src +  8 + i); q3[i] = AG_LD(src + 12 + i);
              q4[i] = AG_LD(src + 16 + i); q5[i] = AG_LD(src + 20 + i);
              q6[i] = AG_LD(src + 24 + i); q7[i] = AG_LD(src + 28 + i);
            }
          }
          bad = 0;
          #pragma unroll
          for (int i = 0; i < 4; ++i){
            bad |= (q0[i] ^ want) & 0xffff0000u; bad |= (q1[i] ^ want) & 0xffff0000u;
            bad |= (q2[i] ^ want) & 0xffff0000u; bad |= (q3[i] ^ want) & 0xffff0000u;
            bad |= (q4[i] ^ want) & 0xffff0000u; bad |= (q5[i] ^ want) & 0xffff0000u;
            bad |= (q6[i] ^ want) & 0xffff0000u; bad |= (q7[i] ^ want) & 0xffff0000u;
          }
        } while (bad && ++guard < 500000L);   // sticky budget: terminates

        bf16x8 v0, v1, v2, v3;
        #pragma unroll
        for (int i = 0; i < 4; ++i){
          v0[i] = (short)(q0[i] & 0xffffu); v0[4+i] = (short)(q1[i] & 0xffffu);
          v1[i] = (short)(q2[i] & 0xffffu); v1[4+i] = (short)(q3[i] & 0xffffu);
          v2[i] = (short)(q4[i] & 0xffffu); v2[4+i] = (short)(q5[i] & 0xffffu);
          v3[i] = (short)(q6[i] & 0xffffu); v3[4+i] = (short)(q7[i] & 0xffffu);
        }
        char* pb = smem + HT(slot) + gg*FRAG + gr*64;
        *(bf16x8*)(pb) = v0; *(bf16x8*)(pb+16) = v1; *(bf16x8*)(pb+32) = v2; *(bf16x8*)(pb+48) = v3;
      }
    }
    __syncthreads();
  }

  // ---- done-rendezvous (tile): all partners finished final gather before we
  //      overwrite slot0 (= h-region) with f32 epilogue values ----
  if (tid == 0) AG_ST(flags + (tile*8 + chunk)*16 + 10, 1u);
  if (tid < 8){
    unsigned v; long g = 0;
    do { v = AG_LD(flags + (tile*8 + tid)*16 + 10); } while (v == 0 && ++g < 10000000L);
  }
  __syncthreads();

  // ---- epilogue ----
  {
    const int row0 = tile*32 + prow;
    #pragma unroll
    for (int r = 0; r < 4; ++r){
      out[(row0 + r)*256 + col]          = hv[r];
      out[262144 + (row0 + r)*256 + col] = cs[r];
    }
  }
}

extern "C" void kernel_launch(void* const* d_in, const int* in_sizes, int n_in,
                              void* d_out, int out_size, void* d_ws, size_t ws_size,
                              hipStream_t stream) {
  (void)in_sizes; (void)n_in; (void)out_size; (void)ws_size;
  const float* obs  = (const float*)d_in[0];
  /* d_in[1] = pooled: unused by reference */
  const float* Wemb = (const float*)d_in[2];
  const float* Bemb = (const float*)d_in[3];
  const float* Wih  = (const float*)d_in[4];
  const float* Whh  = (const float*)d_in[5];
  const float* bih  = (const float*)d_in[6];
  const float* bhh  = (const float*)d_in[7];
  float* out = (float*)d_out;
  unsigned int* flags = (unsigned int*)d_ws;        // 64KB only
  unsigned int* hbuf  = (unsigned int*)d_out;       // tagged exchange lives in d_out

  zero_ws<<<dim3(1056), dim3(512), 0, stream>>>(flags, hbuf);
  lstm_k<<<dim3(256), dim3(256), 0, stream>>>(obs, Wemb, Bemb, Wih, Whh, bih, bhh,
                                              out, flags, hbuf);
}